// Round 6
// baseline (770.369 us; speedup 1.0000x reference)
//
#include <hip/hip_runtime.h>
#include <hip/hip_bf16.h>
#include <cstdint>
#include <cstddef>

// Problem constants
#define E_   8
#define H_   2048
#define I_   2816
#define T_   512
#define NPAIR 1024         // T*K (token,k) pairs

// GEMM tiling: DRAM-page-friendly. BK=256 f32 -> each weight row is read in
// 1KB contiguous chunks (one global_load_lds instruction per row per tile)
// instead of 256B chunks at 8KB stride (which is page-miss-limited to
// ~180 GB/s/XCD and was the shared wall of rounds 0-5).
#define TM   192           // one m-tile per expert w.h.p. -> weights streamed once
#define TN   16
#define BK   256           // f32 per row per tile = 1 KB
#define MT_  3             // m-frags per wave (192 / 4 waves / 16)

typedef __attribute__((ext_vector_type(8))) short          bf16x8;
typedef __attribute__((ext_vector_type(4))) float          f32x4;
typedef __attribute__((ext_vector_type(8))) unsigned short u16x8;

__device__ __forceinline__ unsigned short f2bf(float f){
  union { float f; unsigned u; } a; a.f = f;
  unsigned u = a.u;
  unsigned r = u + 0x7fffu + ((u >> 16) & 1u);   // RNE
  return (unsigned short)(r >> 16);
}

__device__ __forceinline__ void cvt4(u16x8& dst, int base, const float4 v, float s){
  __hip_bfloat162 p0 = __float22bfloat162_rn(float2{v.x*s, v.y*s});
  __hip_bfloat162 p1 = __float22bfloat162_rn(float2{v.z*s, v.w*s});
  union { __hip_bfloat162 b; unsigned u; } a0{p0}, a1{p1};
  dst[base+0] = (unsigned short)(a0.u & 0xffff);
  dst[base+1] = (unsigned short)(a0.u >> 16);
  dst[base+2] = (unsigned short)(a1.u & 0xffff);
  dst[base+3] = (unsigned short)(a1.u >> 16);
}

__device__ __forceinline__ bf16x8 u2b(u16x8 v){
  union { u16x8 u; bf16x8 b; } x; x.u = v; return x.b;
}

// async global->LDS, 16B per lane. Global src is per-lane; LDS dest is
// wave-uniform base + lane*16.
__device__ __forceinline__ void gload_lds16(const void* g, void* l){
  __builtin_amdgcn_global_load_lds(
      (const __attribute__((address_space(1))) unsigned int*)g,
      (__attribute__((address_space(3))) unsigned int*)l, 16, 0, 0);
}

// ---------------------------------------------------------------------------
// Routing: bucket 1024 (t,k) pairs by expert; also inverse map slot-of-pair.
// ---------------------------------------------------------------------------
__global__ void route_kernel(const int* __restrict__ ids,
                             int* __restrict__ offs, int* __restrict__ ptok,
                             int* __restrict__ sop){
  __shared__ int scnt[E_];
  __shared__ int scur[E_];
  const int tid = threadIdx.x;
  if (tid < E_) scnt[tid] = 0;
  __syncthreads();
  const int e = ids[tid];
  atomicAdd(&scnt[e], 1);
  __syncthreads();
  if (tid == 0){
    int s = 0;
    for (int i = 0; i < E_; i++){ offs[i] = s; scur[i] = s; s += scnt[i]; }
    offs[E_] = s;
  }
  __syncthreads();
  const int pos = atomicAdd(&scur[e], 1);
  ptok[pos] = tid >> 1;
  sop[tid]  = pos;
}

// ---------------------------------------------------------------------------
// Prep: gather+convert x rows into slot order, bf16. xg[slot][H]
// ---------------------------------------------------------------------------
__global__ void prep_kernel(const float* __restrict__ x, const int* __restrict__ ptok,
                            unsigned short* __restrict__ xg){
  const int slot = blockIdx.x;
  const int tok  = ptok[slot];
  const int k0   = threadIdx.x * 8;
  const float4 v0 = *(const float4*)(x + (size_t)tok*H_ + k0);
  const float4 v1 = *(const float4*)(x + (size_t)tok*H_ + k0 + 4);
  u16x8 o;
  cvt4(o, 0, v0, 1.f);
  cvt4(o, 4, v1, 1.f);
  *(u16x8*)(xg + (size_t)slot*H_ + k0) = o;
}

// ---------------------------------------------------------------------------
// GEMM1: act[slot,i] = silu(x@Wg^T)*(x@Wu^T).
// B path: per tile, each of the 32 weight rows (16 gate + 16 up) is DMA'd as
// ONE contiguous 1KB chunk (global_load_lds, 64 lanes x 16B) into a
// double-buffered LDS tile. Sequential 1KB-per-page-visit HBM requests ->
// page-hit streaming instead of the 256B/8KB-stride page thrash of earlier
// rounds. One __syncthreads per tile; stage(t+1) issued before comp(t).
// Dequant (x scale -> RNE bf16, bit-identical) at LDS->reg read.
// Bank conflicts: both-sides XOR swizzle, 16B granule, (row&7)<<4.
// XCD pinning: blockIdx.x == expert, gridDim.x == 8 == #XCDs.
// grid: (E=8, I/TN=176, 6), block 256.
// ---------------------------------------------------------------------------
__global__ __launch_bounds__(256, 2)
void gemm1_kernel(const unsigned short* __restrict__ xg, const float* __restrict__ w13,
                  const float* __restrict__ s13, const int* __restrict__ offs,
                  unsigned short* __restrict__ act)
{
  const int e   = blockIdx.x;
  const int off = offs[e];
  const int cnt = offs[e+1] - off;
  const int m0  = blockIdx.z * TM;
  if (m0 >= cnt) return;
  const int rows = min(TM, cnt - m0);
  const int nb   = blockIdx.y * TN;

  __shared__ __align__(16) float Bs[2][2*TN][BK];   // 2 x 32KB = 64 KB

  const int tid  = threadIdx.x;
  const int wv   = tid >> 6;
  const int lane = tid & 63;
  const int quad = lane >> 4;
  const int l16  = lane & 15;

  const float* w13e = w13 + (size_t)e * (2*I_) * H_;
  const float* s13e = s13 + (size_t)e * (2*I_/128) * (H_/128);

  const int s0row = (nb >> 7) * (H_/128);             // gate scale row base
  const int s1row = ((I_/128) + (nb >> 7)) * (H_/128);// up   scale row base

  // Staging: wave wv stages rows [wv*8, wv*8+8), one 1KB instruction per row.
  // Per-lane global src pre-swizzled: (lane*16) ^ ((row&7)<<4) within chunk.
  const char* srcP[8];
  #pragma unroll
  for (int j = 0; j < 8; j++){
    const int r  = wv*8 + j;
    const int gr = (r < TN) ? (nb + r) : (I_ + nb + (r - TN));
    srcP[j] = (const char*)(w13e + (size_t)gr * H_) + (((lane << 4) ^ ((r & 7) << 4)));
  }
  auto stage = [&](int t, int buf){
    #pragma unroll
    for (int j = 0; j < 8; j++)
      gload_lds16(srcP[j] + (size_t)t * (BK*4), &Bs[buf][wv*8 + j][0]);
  };

  // A fragment row pointers (clamped; OOB rows discarded in epilogue)
  const unsigned short* aP[MT_];
  #pragma unroll
  for (int mt = 0; mt < MT_; mt++){
    int sl = off + m0 + wv*(TM/4) + mt*16 + l16;
    sl = min(sl, NPAIR - 1);
    aP[mt] = xg + (size_t)sl * H_ + quad*8;
  }

  f32x4 acc[2][MT_];
  #pragma unroll
  for (int h = 0; h < 2; h++)
    #pragma unroll
    for (int mt = 0; mt < MT_; mt++)
      acc[h][mt] = (f32x4){0.f, 0.f, 0.f, 0.f};

  auto comp = [&](int t, int buf){
    const float sgA = s13e[s0row + 2*t];
    const float sgB = s13e[s0row + 2*t + 1];
    const float suA = s13e[s1row + 2*t];
    const float suB = s13e[s1row + 2*t + 1];
    #pragma unroll
    for (int kc = 0; kc < 8; kc++){              // 8 x K32 steps per tile
      bf16x8 av[MT_];
      #pragma unroll
      for (int mt = 0; mt < MT_; mt++)
        av[mt] = *(const bf16x8*)(aP[mt] + t*BK + kc*32);
      const float sg = (kc < 4) ? sgA : sgB;
      const float su = (kc < 4) ? suA : suB;
      #pragma unroll
      for (int hh = 0; hh < 2; hh++){
        const int row = hh*TN + l16;
        const int xr  = (row & 7) << 2;          // float units (=16B)
        const int cb  = kc*32 + quad*8;
        const float4 F0 = *(const float4*)&Bs[buf][row][(cb)     ^ xr];
        const float4 F1 = *(const float4*)&Bs[buf][row][(cb + 4) ^ xr];
        const float s = hh ? su : sg;
        u16x8 o; cvt4(o, 0, F0, s); cvt4(o, 4, F1, s);
        const bf16x8 bv = u2b(o);
        #pragma unroll
        for (int mt = 0; mt < MT_; mt++)
          acc[hh][mt] = __builtin_amdgcn_mfma_f32_16x16x32_bf16(av[mt], bv, acc[hh][mt], 0, 0, 0);
      }
    }
  };

  const int NT = H_/BK;   // 8
  stage(0, 0);
  __syncthreads();
  int buf = 0;
  for (int t = 0; t < NT; t++){
    if (t+1 < NT) stage(t+1, buf ^ 1);
    comp(t, buf);
    __syncthreads();
    buf ^= 1;
  }

  // epilogue: act = silu(gate)*up
  #pragma unroll
  for (int mt = 0; mt < MT_; mt++){
    #pragma unroll
    for (int r = 0; r < 4; r++){
      const int m = wv*(TM/4) + mt*16 + quad*4 + r;
      if (m < rows){
        const float g = acc[0][mt][r];
        const float u = acc[1][mt][r];
        const float sg2 = g / (1.f + __expf(-g));
        act[(size_t)(off + m0 + m)*I_ + (nb + l16)] = f2bf(sg2 * u);
      }
    }
  }
}

// ---------------------------------------------------------------------------
// GEMM2: buf[slot,h] = act @ W2^T. Same page-friendly structure.
// 16 rows x 1KB per tile, 4 rows staged per wave. 11 tiles (2816 = 11*256).
// grid: (E=8, H/TN=128, 6), block 256.
// ---------------------------------------------------------------------------
__global__ __launch_bounds__(256, 2)
void gemm2_kernel(const unsigned short* __restrict__ act, const float* __restrict__ w2,
                  const float* __restrict__ s2, const int* __restrict__ offs,
                  float* __restrict__ buf_out)
{
  const int e   = blockIdx.x;
  const int off = offs[e];
  const int cnt = offs[e+1] - off;
  const int m0  = blockIdx.z * TM;
  if (m0 >= cnt) return;
  const int rows = min(TM, cnt - m0);
  const int nb   = blockIdx.y * TN;

  __shared__ __align__(16) float Bs[2][TN][BK];   // 2 x 16KB = 32 KB

  const int tid  = threadIdx.x;
  const int wv   = tid >> 6;
  const int lane = tid & 63;
  const int quad = lane >> 4;
  const int l16  = lane & 15;

  const float* w2e = w2 + (size_t)e * H_ * I_;
  const float* s2e = s2 + (size_t)e * (H_/128) * (I_/128);
  const int srow  = (nb >> 7) * (I_/128);

  // Staging: wave wv stages rows [wv*4, wv*4+4), one 1KB instruction per row.
  const char* srcP[4];
  #pragma unroll
  for (int j = 0; j < 4; j++){
    const int r = wv*4 + j;
    srcP[j] = (const char*)(w2e + (size_t)(nb + r) * I_) + (((lane << 4) ^ ((r & 7) << 4)));
  }
  auto stage = [&](int t, int buf){
    #pragma unroll
    for (int j = 0; j < 4; j++)
      gload_lds16(srcP[j] + (size_t)t * (BK*4), &Bs[buf][wv*4 + j][0]);
  };

  const unsigned short* aP[MT_];
  #pragma unroll
  for (int mt = 0; mt < MT_; mt++){
    int sl = off + m0 + wv*(TM/4) + mt*16 + l16;
    sl = min(sl, NPAIR - 1);
    aP[mt] = act + (size_t)sl * I_ + quad*8;
  }

  f32x4 acc[MT_];
  #pragma unroll
  for (int mt = 0; mt < MT_; mt++)
    acc[mt] = (f32x4){0.f, 0.f, 0.f, 0.f};

  auto comp = [&](int t, int buf){
    const float sA = s2e[srow + 2*t];
    const float sB = s2e[srow + 2*t + 1];
    #pragma unroll
    for (int kc = 0; kc < 8; kc++){
      bf16x8 av[MT_];
      #pragma unroll
      for (int mt = 0; mt < MT_; mt++)
        av[mt] = *(const bf16x8*)(aP[mt] + t*BK + kc*32);
      const int row = l16;
      const int xr  = (row & 7) << 2;
      const int cb  = kc*32 + quad*8;
      const float4 F0 = *(const float4*)&Bs[buf][row][(cb)     ^ xr];
      const float4 F1 = *(const float4*)&Bs[buf][row][(cb + 4) ^ xr];
      const float s = (kc < 4) ? sA : sB;
      u16x8 o; cvt4(o, 0, F0, s); cvt4(o, 4, F1, s);
      const bf16x8 bv = u2b(o);
      #pragma unroll
      for (int mt = 0; mt < MT_; mt++)
        acc[mt] = __builtin_amdgcn_mfma_f32_16x16x32_bf16(av[mt], bv, acc[mt], 0, 0, 0);
    }
  };

  const int NT = I_/BK;   // 11
  stage(0, 0);
  __syncthreads();
  int buf = 0;
  for (int t = 0; t < NT; t++){
    if (t+1 < NT) stage(t+1, buf ^ 1);
    comp(t, buf);
    __syncthreads();
    buf ^= 1;
  }

  // epilogue: plain stores per slot row
  #pragma unroll
  for (int mt = 0; mt < MT_; mt++){
    #pragma unroll
    for (int r = 0; r < 4; r++){
      const int m = wv*(TM/4) + mt*16 + quad*4 + r;
      if (m < rows)
        buf_out[(size_t)(off + m0 + m)*H_ + (nb + l16)] = acc[mt][r];
    }
  }
}

// ---------------------------------------------------------------------------
// Combine: out[t,:] = tw[2t]*buf[sop[2t],:] + tw[2t+1]*buf[sop[2t+1],:]
// ---------------------------------------------------------------------------
__global__ void combine_kernel(const float* __restrict__ buf, const int* __restrict__ sop,
                               const float* __restrict__ tw, float* __restrict__ out){
  const int gid = blockIdx.x*256 + threadIdx.x;
  const int t = gid >> 9;
  const int c = gid & 511;
  const int s0 = sop[2*t], s1 = sop[2*t+1];
  const float w0 = tw[2*t], w1 = tw[2*t+1];
  const float4 v0 = ((const float4*)buf)[(size_t)s0*(H_/4) + c];
  const float4 v1 = ((const float4*)buf)[(size_t)s1*(H_/4) + c];
  float4 o;
  o.x = w0*v0.x + w1*v1.x;
  o.y = w0*v0.y + w1*v1.y;
  o.z = w0*v0.z + w1*v1.z;
  o.w = w0*v0.w + w1*v1.w;
  ((float4*)out)[gid] = o;
}

// ---------------------------------------------------------------------------
extern "C" void kernel_launch(void* const* d_in, const int* in_sizes, int n_in,
                              void* d_out, int out_size, void* d_ws, size_t ws_size,
                              hipStream_t stream){
  const float* x   = (const float*)d_in[0];
  const int*   ids = (const int*)  d_in[1];
  const float* tw  = (const float*)d_in[2];
  const float* w13 = (const float*)d_in[3];
  const float* s13 = (const float*)d_in[4];
  const float* w2  = (const float*)d_in[5];
  const float* s2  = (const float*)d_in[6];
  float* out = (float*)d_out;

  char* ws = (char*)d_ws;
  int* offs = (int*)ws;                                   // 9 ints
  int* ptok = (int*)(ws + 64);                            // 1024 ints
  int* sop  = (int*)(ws + 64 + 4096);                     // 1024 ints
  unsigned short* xg  = (unsigned short*)(ws + 16384);    // [1024][H] bf16 (aliased by buf)
  float*          buf = (float*)(ws + 16384);             // [1024][H] f32
  unsigned short* act = (unsigned short*)(ws + 16384 + (size_t)NPAIR*H_*4);  // [1024][I] bf16

  route_kernel  <<<1, NPAIR, 0, stream>>>(ids, offs, ptok, sop);
  prep_kernel   <<<NPAIR, 256, 0, stream>>>(x, ptok, xg);
  gemm1_kernel  <<<dim3(E_, I_/TN, (NPAIR + TM - 1)/TM), 256, 0, stream>>>(xg, w13, s13, offs, act);
  gemm2_kernel  <<<dim3(E_, H_/TN, (NPAIR + TM - 1)/TM), 256, 0, stream>>>(act, w2, s2, offs, buf);
  combine_kernel<<<(T_*H_/4)/256, 256, 0, stream>>>(buf, sop, tw, out);
}